// Round 8
// baseline (4404.572 us; speedup 1.0000x reference)
//
#include <hip/hip_runtime.h>
#include <hip/hip_fp16.h>

#define B_SZ 64
#define T_SZ 2048
#define D_SZ 256
#define H_SZ 256
#define G3   768
#define M_SZ (B_SZ * T_SZ) // 131072
#define NB   8             // batches per recurrence block
#define HP   264           // padded h row length in halves (528B stride, b128-conflict-free)

typedef _Float16 half4v __attribute__((ext_vector_type(4)));
typedef _Float16 half8v __attribute__((ext_vector_type(8)));
typedef float    f32x4  __attribute__((ext_vector_type(4)));

static __device__ __forceinline__ float h2f(ushort u) {
  return (float)__builtin_bit_cast(_Float16, u);
}
static __device__ __forceinline__ ushort f2h(float x) {
  return __builtin_bit_cast(ushort, (_Float16)x);
}
static __device__ __forceinline__ float fast_rcp(float x) {
  return __builtin_amdgcn_rcpf(x);
}

// ---------- prep 1: Wx f32 -> f16 (GEMM B operand) ----------
__global__ void prep_wx(const float* __restrict__ Wx, ushort* __restrict__ Wxh) {
  int i = blockIdx.x * 256 + threadIdx.x;
  if (i < G3 * D_SZ) Wxh[i] = f2h(Wx[i]);
}

// ---------- prep 2: Wh -> MFMA B-fragment order ----------
// gru_rec wave w, lane l needs, for ct in [0,12) and ks in [0,8), the uint4 at
// Wb[((w*12+ct)*8+ks)*64 + l]. Fragment: B[k = ks*32+(l>>4)*8+e][col], col =
// gate*256 + (4w+(ct&3))*16 + (l&15), gate = ct>>2; B[k][col] = Wh[col][k].
__global__ void prep_wb(const float* __restrict__ Wh, uint* __restrict__ Wb) {
  int F = blockIdx.x * 256 + threadIdx.x; // dword index 0..98303
  int d = F & 3;
  int l = (F >> 2) & 63;
  int ks = (F >> 8) & 7;
  int ctf = F >> 11;            // 0..47
  int w = ctf / 12, rem = ctf % 12;
  int gate = rem >> 2, i = rem & 3;
  int col = gate * 256 + (4 * w + i) * 16 + (l & 15); // Wh row
  int k0 = ks * 32 + (l >> 4) * 8 + 2 * d;
  float a = Wh[(size_t)col * D_SZ + k0];
  float b = Wh[(size_t)col * D_SZ + k0 + 1];
  Wb[F] = (uint)f2h(a) | ((uint)f2h(b) << 16);
}

// ---------- GEMM: xs2[t][b][col] = inputs[b,t,:] . Wx[col,:] + bx + (bh for r,u) ----------
__global__ __launch_bounds__(256) void gemm_x(
    const float* __restrict__ A,   // [M_SZ, 256] f32
    const ushort* __restrict__ Bw, // Wx f16 [768, 256]
    const float* __restrict__ bx,  // [768]
    const float* __restrict__ bh,  // [768] (r,u parts folded here)
    ushort* __restrict__ xs2) {    // [T][64][768] f16
  __shared__ _Float16 As[128][72];
  __shared__ _Float16 Bs[256][72];
  const int nt = blockIdx.x, mt = blockIdx.y;
  const int tid = threadIdx.x;
  const int lane = tid & 63, wv = tid >> 6;
  const int wr = (wv >> 1) * 64, wc = (wv & 1) * 128;
  const int l15 = lane & 15, l4 = lane >> 4;
  f32x4 acc[4][8] = {};
  for (int kt = 0; kt < 4; kt++) {
#pragma unroll
    for (int i = 0; i < 8; i++) {
      int f = tid + i * 256;
      int r = f >> 4, c4 = f & 15;
      float4 v = *(const float4*)(A + (size_t)(mt * 128 + r) * D_SZ + kt * 64 + c4 * 4);
      half4v h;
      h[0] = (_Float16)v.x; h[1] = (_Float16)v.y;
      h[2] = (_Float16)v.z; h[3] = (_Float16)v.w;
      *(half4v*)&As[r][c4 * 4] = h;
    }
#pragma unroll
    for (int i = 0; i < 8; i++) {
      int f = tid + i * 256;
      int r = f >> 3, c8 = f & 7;
      uint4 v = *(const uint4*)(Bw + (size_t)(nt * 256 + r) * D_SZ + kt * 64 + c8 * 8);
      *(uint4*)&Bs[r][c8 * 8] = v;
    }
    __syncthreads();
#pragma unroll
    for (int kk = 0; kk < 2; kk++) {
      half8v af[4], bf[8];
#pragma unroll
      for (int m = 0; m < 4; m++)
        af[m] = *(const half8v*)&As[wr + m * 16 + l15][kk * 32 + l4 * 8];
#pragma unroll
      for (int n = 0; n < 8; n++)
        bf[n] = *(const half8v*)&Bs[wc + n * 16 + l15][kk * 32 + l4 * 8];
#pragma unroll
      for (int m = 0; m < 4; m++) {
#pragma unroll
        for (int n = 0; n < 8; n++) {
          acc[m][n] = __builtin_amdgcn_mfma_f32_16x16x32_f16(af[m], bf[n], acc[m][n], 0, 0, 0);
        }
      }
    }
    __syncthreads();
  }
#pragma unroll
  for (int n = 0; n < 8; n++) {
    int col = nt * 256 + wc + n * 16 + l15;
    float bias = bx[col] + (col < 512 ? bh[col] : 0.f);
#pragma unroll
    for (int m = 0; m < 4; m++) {
#pragma unroll
      for (int v4 = 0; v4 < 4; v4++) {
        int row = mt * 128 + wr + m * 16 + l4 * 4 + v4; // m index = b*T + t
        int bb = row >> 11, tt = row & 2047;
        xs2[((size_t)tt * 64 + bb) * G3 + col] = f2h(acc[m][n][v4] + bias);
      }
    }
  }
}

// ---------- recurrence: 8 blocks x 256 threads; Wh in AGPRs consumed by MFMA ----
// Per block: 8 batches. Per step: h[8x256] (LDS, f16, padded rows) x Wh^T via
// 96 mfma_16x16x32_f16 per wave (12 col-tiles x 8 k-slices), B-fragments
// persistent in 384 AGPRs/thread (MFMA reads AGPR natively -> no move tax).
// Acc redistribution via 2 shfl_xor(32) per tile; gates on all 64 lanes
// (8 h/lane); h double-buffered; x staged 1 step ahead; 1 barrier/step.
__global__ __launch_bounds__(256, 1) void gru_rec(
    const ushort* __restrict__ xs2, // [T][64][768] f16 (r,u have bh folded)
    const uint* __restrict__ Wb,    // B fragments
    const float* __restrict__ bh,   // [768] (only n-part used here)
    const float* __restrict__ hid,  // [1, B, 256]
    float* __restrict__ out) {      // [B, T, 256] f32
  const int b0 = blockIdx.x * NB;
  const int tid = threadIdx.x;
  const int l = tid & 63, w = tid >> 6;
  const int l15 = l & 15;

  __shared__ ushort hbuf[2][16][HP];     // 16.9 KB (rows 8..15 stay zero)
  __shared__ ushort xbuf[2][NB * G3];    // 24 KB

  // persistent B fragments -> AGPRs
  uint4 Bf[12][8];
  {
    const uint4* wb = (const uint4*)Wb;
#pragma unroll
    for (int ct = 0; ct < 12; ct++)
#pragma unroll
      for (int ks = 0; ks < 8; ks++)
        Bf[ct][ks] = wb[(size_t)((w * 12 + ct) * 8 + ks) * 64 + l];
  }

  // gate-lane batch mapping: quadrant qd -> batches {0,1},{4,5},{2,3},{6,7}
  const int qd = l >> 4;
  const int bbase = (qd & 1) * 4 + (qd & 2);

  float bhn[4], hreg[4][2];
#pragma unroll
  for (int i = 0; i < 4; i++) {
    int unit = (4 * w + i) * 16 + l15;
    bhn[i] = bh[512 + unit];
#pragma unroll
    for (int be = 0; be < 2; be++)
      hreg[i][be] = hid[(b0 + bbase + be) * H_SZ + unit];
  }

  // zero hbuf (both buffers; rows 8..15 must be 0 for the M=16 MFMA)
  {
    uint* hz = (uint*)hbuf;
    for (int idx = tid; idx < 2 * 16 * HP / 2; idx += 256) hz[idx] = 0u;
  }
  __syncthreads();
  for (int idx = tid; idx < NB * H_SZ; idx += 256) {
    int bb = idx >> 8, u = idx & 255;
    hbuf[0][bb][u] = f2h(hid[(b0 + bb) * H_SZ + u]);
  }
  // stage x(0)
  {
    const uint4* gx = (const uint4*)(xs2 + (size_t)b0 * G3);
    uint4* xb = (uint4*)xbuf[0];
    xb[tid] = gx[tid]; xb[tid + 256] = gx[tid + 256]; xb[tid + 512] = gx[tid + 512];
  }
  __syncthreads();

#pragma unroll 1
  for (int t = 0; t < T_SZ; t++) {
    const int cur = t & 1, nxt = cur ^ 1;

    // 1) issue staging loads for x(t+1) (latency hides under MFMA+gates)
    int tn = (t + 1 < T_SZ) ? t + 1 : t;
    const uint4* gx = (const uint4*)(xs2 + ((size_t)tn * 64 + b0) * G3);
    uint4 xg0 = gx[tid], xg1 = gx[tid + 256], xg2 = gx[tid + 512];

    // 2) A fragments (rolling 3-deep) + 96 MFMA
    f32x4 acc[12];
    half8v Af[8];
    const ushort* hrow = &hbuf[cur][l15][(l >> 4) * 8];
#pragma unroll
    for (int ks = 0; ks < 3; ks++)
      Af[ks] = __builtin_bit_cast(half8v, *(const uint4*)(hrow + ks * 32));
#pragma unroll
    for (int ct = 0; ct < 12; ct++)
      acc[ct] = __builtin_amdgcn_mfma_f32_16x16x32_f16(
          Af[0], __builtin_bit_cast(half8v, Bf[ct][0]),
          (f32x4){0.f, 0.f, 0.f, 0.f}, 0, 0, 0);
#pragma unroll
    for (int ks = 1; ks < 8; ks++) {
      if (ks + 2 < 8)
        Af[ks + 2] = __builtin_bit_cast(half8v, *(const uint4*)(hrow + (ks + 2) * 32));
#pragma unroll
      for (int ct = 0; ct < 12; ct++)
        acc[ct] = __builtin_amdgcn_mfma_f32_16x16x32_f16(
            Af[ks], __builtin_bit_cast(half8v, Bf[ct][ks]), acc[ct], 0, 0, 0);
    }

    // 3) redistribute accs to all 64 lanes + 4) gates (8 h per lane)
#pragma unroll
    for (int i = 0; i < 4; i++) {
      int unit = (4 * w + i) * 16 + l15;
      float v[3][2];
#pragma unroll
      for (int g = 0; g < 3; g++) {
        f32x4 a = acc[g * 4 + i];
        float s2 = __shfl_xor(a[2], 32);
        float s3 = __shfl_xor(a[3], 32);
        v[g][0] = (l < 32) ? a[0] : s2;
        v[g][1] = (l < 32) ? a[1] : s3;
      }
#pragma unroll
      for (int be = 0; be < 2; be++) {
        int bb = bbase + be;
        const ushort* xp = &xbuf[cur][bb * G3 + unit];
        float xr = h2f(xp[0]), xu = h2f(xp[256]), xn = h2f(xp[512]);
        float rr = fast_rcp(1.f + __expf(-(xr + v[0][be])));
        float uu = fast_rcp(1.f + __expf(-(xu + v[1][be])));
        float arg = xn + rr * (v[2][be] + bhn[i]);
        float e2 = __expf(-2.f * fabsf(arg));
        float th = copysignf((1.f - e2) * fast_rcp(1.f + e2), arg);
        float hn = th + uu * (hreg[i][be] - th);
        hreg[i][be] = hn;
        out[((size_t)(b0 + bb) * T_SZ + t) * H_SZ + unit] = hn; // fire-and-forget
        hbuf[nxt][bb][unit] = f2h(hn);
      }
    }

    // 5) commit staged x(t+1) (compiler inserts the vmcnt dep-wait)
    {
      uint4* xb = (uint4*)xbuf[nxt];
      xb[tid] = xg0; xb[tid + 256] = xg1; xb[tid + 512] = xg2;
    }
    asm volatile("s_waitcnt lgkmcnt(0)" ::: "memory");
    __builtin_amdgcn_s_barrier();
  }
}

extern "C" void kernel_launch(void* const* d_in, const int* in_sizes, int n_in,
                              void* d_out, int out_size, void* d_ws, size_t ws_size,
                              hipStream_t stream) {
  const float* inp = (const float*)d_in[0]; // [B,T,D] f32
  const float* hid = (const float*)d_in[1]; // [1,B,H] f32
  const float* Wx  = (const float*)d_in[2]; // [768,256] f32
  const float* bx  = (const float*)d_in[3]; // [768] f32
  const float* Wh  = (const float*)d_in[4]; // [768,256] f32
  const float* bh  = (const float*)d_in[5]; // [768] f32
  float* out = (float*)d_out;

  // workspace: xs2 f16 [T][64][768] (192 MiB), Wxh f16 (384 KiB), Wb uint (384 KiB)
  char* ws = (char*)d_ws;
  ushort* xs2 = (ushort*)ws;
  size_t xs_bytes = (size_t)M_SZ * G3 * sizeof(ushort);
  ushort* Wxh = (ushort*)(ws + xs_bytes);
  uint* Wb = (uint*)(ws + xs_bytes + (size_t)G3 * D_SZ * sizeof(ushort));

  prep_wx<<<768, 256, 0, stream>>>(Wx, Wxh);
  prep_wb<<<384, 256, 0, stream>>>(Wh, Wb);
  gemm_x<<<dim3(3, 1024), 256, 0, stream>>>(inp, Wxh, bx, bh, xs2);
  gru_rec<<<B_SZ / NB, 256, 0, stream>>>(xs2, Wb, bh, hid, out);
}

// Round 11
// 3363.511 us; speedup vs baseline: 1.3095x; 1.3095x over previous
//
#include <hip/hip_runtime.h>
#include <hip/hip_fp16.h>

#define B_SZ 64
#define T_SZ 2048
#define D_SZ 256
#define H_SZ 256
#define G3   768
#define M_SZ (B_SZ * T_SZ) // 131072
#define NB   8             // batches per recurrence block
#define HP   264           // padded h row (528B stride)
#define XP   776           // padded x row (1552B stride)

typedef _Float16 half4v __attribute__((ext_vector_type(4)));
typedef _Float16 half8v __attribute__((ext_vector_type(8)));
typedef float    f32x4  __attribute__((ext_vector_type(4)));

static __device__ __forceinline__ float h2f(ushort u) {
  return (float)__builtin_bit_cast(_Float16, u);
}
static __device__ __forceinline__ ushort f2h(float x) {
  return __builtin_bit_cast(ushort, (_Float16)x);
}
static __device__ __forceinline__ float fast_rcp(float x) {
  return __builtin_amdgcn_rcpf(x);
}

// direct HBM->LDS, 16B per active lane (dest = wave-uniform base + lane*16)
#define GLOAD_LDS16(g, l)                                                     \
  __builtin_amdgcn_global_load_lds(                                           \
      (const __attribute__((address_space(1))) unsigned int*)(g),             \
      (__attribute__((address_space(3))) unsigned int*)(l), 16, 0, 0)

// ---------- prep 1: Wx f32 -> f16 (GEMM B operand) ----------
__global__ void prep_wx(const float* __restrict__ Wx, ushort* __restrict__ Wxh) {
  int i = blockIdx.x * 256 + threadIdx.x;
  if (i < G3 * D_SZ) Wxh[i] = f2h(Wx[i]);
}

// ---------- prep 2: Wh -> MFMA B fragments ----------
// gru_rec wave w (0..7), col-tiles ct=0..5: gate g=ct>>1, i=ct&1,
// cols = g*256 + (2w+i)*16 + l15. Lane l holds B[k = ks*32+(l>>4)*8+e][col],
// e=0..7 (f16 pairs; dword d holds e=2d,2d+1). uint4 idx ((w*6+ct)*8+ks)*64+l.
// (fragment math identical to round 8, which PASSED end-to-end)
__global__ void prep_wb(const float* __restrict__ Wh, uint* __restrict__ Wb) {
  int F = blockIdx.x * 256 + threadIdx.x; // dword 0..98303
  int d = F & 3;
  int l = (F >> 2) & 63;
  int ks = (F >> 8) & 7;
  int wct = F >> 11;             // 0..47
  int w = wct / 6, ct = wct % 6;
  int g = ct >> 1, i = ct & 1;
  int col = g * 256 + (2 * w + i) * 16 + (l & 15); // Wh row index
  int k0 = ks * 32 + (l >> 4) * 8 + 2 * d;
  float a = Wh[(size_t)col * D_SZ + k0];
  float b = Wh[(size_t)col * D_SZ + k0 + 1];
  Wb[F] = (uint)f2h(a) | ((uint)f2h(b) << 16);
}

// ---------- GEMM: xs2[t][b][col] = x@Wx^T + bx (+bh for r,u), f16 ----------
__global__ __launch_bounds__(256) void gemm_x(
    const float* __restrict__ A,   // [M_SZ, 256] f32
    const ushort* __restrict__ Bw, // Wx f16 [768, 256]
    const float* __restrict__ bx,  // [768]
    const float* __restrict__ bh,  // [768]
    ushort* __restrict__ xs2) {    // [T][64][768] f16
  __shared__ _Float16 As[128][72];
  __shared__ _Float16 Bs[256][72];
  const int nt = blockIdx.x, mt = blockIdx.y;
  const int tid = threadIdx.x;
  const int lane = tid & 63, wv = tid >> 6;
  const int wr = (wv >> 1) * 64, wc = (wv & 1) * 128;
  const int l15 = lane & 15, l4 = lane >> 4;
  f32x4 acc[4][8] = {};
  for (int kt = 0; kt < 4; kt++) {
#pragma unroll
    for (int i = 0; i < 8; i++) {
      int f = tid + i * 256;
      int r = f >> 4, c4 = f & 15;
      float4 v = *(const float4*)(A + (size_t)(mt * 128 + r) * D_SZ + kt * 64 + c4 * 4);
      half4v h;
      h[0] = (_Float16)v.x; h[1] = (_Float16)v.y;
      h[2] = (_Float16)v.z; h[3] = (_Float16)v.w;
      *(half4v*)&As[r][c4 * 4] = h;
    }
#pragma unroll
    for (int i = 0; i < 8; i++) {
      int f = tid + i * 256;
      int r = f >> 3, c8 = f & 7;
      uint4 v = *(const uint4*)(Bw + (size_t)(nt * 256 + r) * D_SZ + kt * 64 + c8 * 8);
      *(uint4*)&Bs[r][c8 * 8] = v;
    }
    __syncthreads();
#pragma unroll
    for (int kk = 0; kk < 2; kk++) {
      half8v af[4], bf[8];
#pragma unroll
      for (int m = 0; m < 4; m++)
        af[m] = *(const half8v*)&As[wr + m * 16 + l15][kk * 32 + l4 * 8];
#pragma unroll
      for (int n = 0; n < 8; n++)
        bf[n] = *(const half8v*)&Bs[wc + n * 16 + l15][kk * 32 + l4 * 8];
#pragma unroll
      for (int m = 0; m < 4; m++) {
#pragma unroll
        for (int n = 0; n < 8; n++) {
          acc[m][n] = __builtin_amdgcn_mfma_f32_16x16x32_f16(af[m], bf[n], acc[m][n], 0, 0, 0);
        }
      }
    }
    __syncthreads();
  }
#pragma unroll
  for (int n = 0; n < 8; n++) {
    int col = nt * 256 + wc + n * 16 + l15;
    float bias = bx[col] + (col < 512 ? bh[col] : 0.f);
#pragma unroll
    for (int m = 0; m < 4; m++) {
#pragma unroll
      for (int v4 = 0; v4 < 4; v4++) {
        int row = mt * 128 + wr + m * 16 + l4 * 4 + v4; // = b*T + t
        int bb = row >> 11, tt = row & 2047;
        xs2[((size_t)tt * 64 + bb) * G3 + col] = f2h(acc[m][n][v4] + bias);
      }
    }
  }
}

// ---------- recurrence: 8 blocks x 512 threads (8 waves, 2 waves/SIMD) -------
// Wave w owns units [(2w)*16,(2w+2)*16) x 3 gates. 48 NAMED uint4 B-fragments
// (192 regs) homed in the unified file's acc half, consumed NATIVELY by the
// MFMA builtin (gfx950: v_mfma reads AGPR/VGPR alike -> no move tax; round-8
// proved correctness, its cost was 640-reg oversubscription @1 wave/SIMD).
// h double-buffered in LDS; x staged 2 ahead via global_load_lds ring with
// counted vmcnt(7); one lgkm-only barrier per step.
__global__ __launch_bounds__(512)
__attribute__((amdgpu_waves_per_eu(2, 2)))
void gru_rec(
    const ushort* __restrict__ xs2, // [T][64][768] f16 (r,u have bh folded)
    const uint* __restrict__ Wb,    // B fragments
    const float* __restrict__ bh,   // [768] (n-part used)
    const float* __restrict__ hid,  // [1, B, 256]
    float* __restrict__ out) {      // [B, T, 256] f32
  const int b0 = blockIdx.x * NB;
  const int tid = threadIdx.x;
  const int l = tid & 63, w = tid >> 6;
  const int l15 = l & 15;
  const int qd = l >> 4;
  const int bbase = (qd & 1) * 4 + (qd & 2); // qd 0,1,2,3 -> {0,1},{4,5},{2,3},{6,7}

  __shared__ ushort hbuf[2][16][HP]; // rows 8..15 stay zero
  __shared__ ushort xbuf[3][NB][XP];

  // ---- prologue: issue x(0),x(1) DMA ----
#pragma unroll
  for (int pt = 0; pt < 2; pt++) {
    const ushort* src = xs2 + ((size_t)pt * 64 + b0 + w) * G3;
    if (l < 32) {
#pragma unroll
      for (int c = 0; c < 3; c++)
        GLOAD_LDS16(src + c * 256 + l * 8, &xbuf[pt][w][c * 256]);
    }
  }

  // ---- 48 named B-fragment values ----
  const uint4* wb = (const uint4*)Wb;
#define WIDX(ct, ks) ((size_t)((w * 6 + (ct)) * 8 + (ks)) * 64 + l)
#define BF_LOAD(ct)                                                           \
  uint4 B##ct##_0 = wb[WIDX(ct, 0)], B##ct##_1 = wb[WIDX(ct, 1)],             \
        B##ct##_2 = wb[WIDX(ct, 2)], B##ct##_3 = wb[WIDX(ct, 3)],             \
        B##ct##_4 = wb[WIDX(ct, 4)], B##ct##_5 = wb[WIDX(ct, 5)],             \
        B##ct##_6 = wb[WIDX(ct, 6)], B##ct##_7 = wb[WIDX(ct, 7)];
  BF_LOAD(0) BF_LOAD(1) BF_LOAD(2) BF_LOAD(3) BF_LOAD(4) BF_LOAD(5)

  const float bhn0 = bh[512 + (2 * w) * 16 + l15];
  const float bhn1 = bh[512 + (2 * w + 1) * 16 + l15];
  float h00 = hid[(b0 + bbase + 0) * H_SZ + (2 * w) * 16 + l15];
  float h01 = hid[(b0 + bbase + 1) * H_SZ + (2 * w) * 16 + l15];
  float h10 = hid[(b0 + bbase + 0) * H_SZ + (2 * w + 1) * 16 + l15];
  float h11 = hid[(b0 + bbase + 1) * H_SZ + (2 * w + 1) * 16 + l15];

  // per-thread out pointers (incremented by H_SZ floats per step)
  float* o00 = out + ((size_t)(b0 + bbase) * T_SZ) * H_SZ + (2 * w) * 16 + l15;
  float* o01 = out + ((size_t)(b0 + bbase + 1) * T_SZ) * H_SZ + (2 * w) * 16 + l15;
  float* o10 = o00 + 16;
  float* o11 = o01 + 16;

  { // zero both h buffers, then fill rows 0..7 of buffer 0
    uint* hz = (uint*)hbuf;
    for (int idx = tid; idx < 2 * 16 * HP / 2; idx += 512) hz[idx] = 0u;
  }
  __syncthreads();
  for (int idx = tid; idx < NB * H_SZ; idx += 512) {
    int bb = idx >> 8, u = idx & 255;
    hbuf[0][bb][u] = f2h(hid[(b0 + bb) * H_SZ + u]);
  }
  __syncthreads(); // full drain: x(0),x(1),h ready

  int c0 = 0, c2 = 2; // x ring: read idx, write idx

#define MFMA1(acc_, af_, bf_)                                                 \
  acc_ = __builtin_amdgcn_mfma_f32_16x16x32_f16(                              \
      (af_), __builtin_bit_cast(half8v, (bf_)), (acc_), 0, 0, 0)
#define MFMA_GRP(ks_, af_)                                                    \
  MFMA1(acc0, af_, B0_##ks_); MFMA1(acc1, af_, B1_##ks_);                     \
  MFMA1(acc2, af_, B2_##ks_); MFMA1(acc3, af_, B3_##ks_);                     \
  MFMA1(acc4, af_, B4_##ks_); MFMA1(acc5, af_, B5_##ks_);
#define AF_LD(ks_) __builtin_bit_cast(half8v, *(const uint4*)(hrow + (ks_) * 32))

#pragma unroll 1
  for (int t = 0; t < T_SZ; t++) {
    const int cur = t & 1, nxt = cur ^ 1;

    // 1) DMA x(t+2) -> xbuf[c2] (wave w stages batch row w)
    {
      int tn = t + 2; if (tn >= T_SZ) tn = T_SZ - 1;
      const ushort* src = xs2 + ((size_t)tn * 64 + b0 + w) * G3;
      if (l < 32) {
#pragma unroll
        for (int c = 0; c < 3; c++)
          GLOAD_LDS16(src + c * 256 + l * 8, &xbuf[c2][w][c * 256]);
      }
    }

    // 2) 48 MFMA, named B-fragments consumed in place, 2-deep Af ring
    const ushort* hrow = &hbuf[cur][l15][qd * 8];
    f32x4 acc0 = {0.f, 0.f, 0.f, 0.f}, acc1 = acc0, acc2 = acc0,
          acc3 = acc0, acc4 = acc0, acc5 = acc0;
    half8v af0 = AF_LD(0), af1 = AF_LD(1);
    __builtin_amdgcn_s_setprio(1);
    MFMA_GRP(0, af0) af0 = AF_LD(2);
    MFMA_GRP(1, af1) af1 = AF_LD(3);
    MFMA_GRP(2, af0) af0 = AF_LD(4);
    MFMA_GRP(3, af1) af1 = AF_LD(5);
    MFMA_GRP(4, af0) af0 = AF_LD(6);
    MFMA_GRP(5, af1) af1 = AF_LD(7);
    MFMA_GRP(6, af0)
    MFMA_GRP(7, af1)
    __builtin_amdgcn_s_setprio(0);

    // 3) gates (rows->batches via shfl; identical mapping passed in round 8)
#define GATES(i_, aR, aU, aN, hA, hB, bhn_, oA, oB)                           \
    {                                                                         \
      int unit = (2 * w + (i_)) * 16 + l15;                                   \
      float rs2 = __shfl_xor(aR[2], 32), rs3 = __shfl_xor(aR[3], 32);         \
      float us2 = __shfl_xor(aU[2], 32), us3 = __shfl_xor(aU[3], 32);         \
      float ns2 = __shfl_xor(aN[2], 32), ns3 = __shfl_xor(aN[3], 32);         \
      float vr0 = (l < 32) ? aR[0] : rs2, vr1 = (l < 32) ? aR[1] : rs3;       \
      float vu0 = (l < 32) ? aU[0] : us2, vu1 = (l < 32) ? aU[1] : us3;       \
      float vn0 = (l < 32) ? aN[0] : ns2, vn1 = (l < 32) ? aN[1] : ns3;       \
      const ushort* x3a = &xbuf[c0][bbase][unit];                             \
      const ushort* x3b = &xbuf[c0][bbase + 1][unit];                         \
      {                                                                       \
        float rr = fast_rcp(1.f + __expf(-(h2f(x3a[0]) + vr0)));              \
        float uu = fast_rcp(1.f + __expf(-(h2f(x3a[256]) + vu0)));            \
        float arg = h2f(x3a[512]) + rr * (vn0 + (bhn_));                      \
        float e2 = __expf(-2.f * fabsf(arg));                                 \
        float th = copysignf((1.f - e2) * fast_rcp(1.f + e2), arg);           \
        float hn = th + uu * ((hA) - th);                                     \
        (hA) = hn;                                                            \
        *(oA) = hn;                                                           \
        hbuf[nxt][bbase][unit] = f2h(hn);                                     \
      }                                                                       \
      {                                                                       \
        float rr = fast_rcp(1.f + __expf(-(h2f(x3b[0]) + vr1)));              \
        float uu = fast_rcp(1.f + __expf(-(h2f(x3b[256]) + vu1)));            \
        float arg = h2f(x3b[512]) + rr * (vn1 + (bhn_));                      \
        float e2 = __expf(-2.f * fabsf(arg));                                 \
        float th = copysignf((1.f - e2) * fast_rcp(1.f + e2), arg);           \
        float hn = th + uu * ((hB) - th);                                     \
        (hB) = hn;                                                            \
        *(oB) = hn;                                                           \
        hbuf[nxt][bbase + 1][unit] = f2h(hn);                                 \
      }                                                                       \
    }
    GATES(0, acc0, acc2, acc4, h00, h01, bhn0, o00, o01)
    GATES(1, acc1, acc3, acc5, h10, h11, bhn1, o10, o11)
#undef GATES
    o00 += H_SZ; o01 += H_SZ; o10 += H_SZ; o11 += H_SZ;

    // 4) counted vmcnt: newest 7 = this step's 3 loads + 4 stores ->
    //    x(t+1)'s DMA (older) has landed. LDS fence + barrier.
    asm volatile("s_waitcnt vmcnt(7)" ::: "memory");
    asm volatile("s_waitcnt lgkmcnt(0)" ::: "memory");
    __builtin_amdgcn_s_barrier();
    c0 = (c0 == 2) ? 0 : c0 + 1;
    c2 = (c2 == 2) ? 0 : c2 + 1;
  }
}

extern "C" void kernel_launch(void* const* d_in, const int* in_sizes, int n_in,
                              void* d_out, int out_size, void* d_ws, size_t ws_size,
                              hipStream_t stream) {
  const float* inp = (const float*)d_in[0]; // [B,T,D] f32
  const float* hid = (const float*)d_in[1]; // [1,B,H] f32
  const float* Wx  = (const float*)d_in[2]; // [768,256] f32
  const float* bx  = (const float*)d_in[3]; // [768] f32
  const float* Wh  = (const float*)d_in[4]; // [768,256] f32
  const float* bh  = (const float*)d_in[5]; // [768] f32
  float* out = (float*)d_out;

  // workspace: xs2 f16 [T][64][768] (192 MiB), Wxh f16 (384 KiB), Wb uint (384 KiB)
  char* ws = (char*)d_ws;
  ushort* xs2 = (ushort*)ws;
  size_t xs_bytes = (size_t)M_SZ * G3 * sizeof(ushort);
  ushort* Wxh = (ushort*)(ws + xs_bytes);
  uint* Wb = (uint*)(ws + xs_bytes + (size_t)G3 * D_SZ * sizeof(ushort));

  prep_wx<<<768, 256, 0, stream>>>(Wx, Wxh);
  prep_wb<<<384, 256, 0, stream>>>(Wh, Wb);
  gemm_x<<<dim3(3, 1024), 256, 0, stream>>>(inp, Wxh, bx, bh, xs2);
  gru_rec<<<B_SZ / NB, 512, 0, stream>>>(xs2, Wb, bh, hid, out);
}

// Round 12
// 2948.468 us; speedup vs baseline: 1.4939x; 1.1408x over previous
//
#include <hip/hip_runtime.h>
#include <hip/hip_fp16.h>

#define B_SZ 64
#define T_SZ 2048
#define D_SZ 256
#define H_SZ 256
#define G3   768
#define M_SZ (B_SZ * T_SZ) // 131072

typedef _Float16 half2v __attribute__((ext_vector_type(2)));
typedef _Float16 half4v __attribute__((ext_vector_type(4)));
typedef _Float16 half8v __attribute__((ext_vector_type(8)));
typedef float    f32x4  __attribute__((ext_vector_type(4)));

#if defined(__has_attribute)
#  if __has_attribute(amdgpu_num_vgpr)
#    define NUM_VGPR(n) __attribute__((amdgpu_num_vgpr(n)))
#  else
#    define NUM_VGPR(n)
#  endif
#  if __has_attribute(amdgpu_agpr_alloc)
#    define NO_AGPR __attribute__((amdgpu_agpr_alloc(0)))
#  else
#    define NO_AGPR
#  endif
#else
#  define NUM_VGPR(n)
#  define NO_AGPR
#endif

static __device__ __forceinline__ float fdot2f(uint a, uint b, float acc) {
#if __has_builtin(__builtin_amdgcn_fdot2)
  return __builtin_amdgcn_fdot2(__builtin_bit_cast(half2v, a),
                                __builtin_bit_cast(half2v, b), acc, false);
#else
  half2v av = __builtin_bit_cast(half2v, a), bv = __builtin_bit_cast(half2v, b);
  acc = fmaf((float)av[0], (float)bv[0], acc);
  acc = fmaf((float)av[1], (float)bv[1], acc);
  return acc;
#endif
}

static __device__ __forceinline__ float h2f(ushort u) {
  return (float)__builtin_bit_cast(_Float16, u);
}
static __device__ __forceinline__ ushort f2h(float x) {
  return __builtin_bit_cast(ushort, (_Float16)x);
}
static __device__ __forceinline__ float fast_rcp(float x) {
  return __builtin_amdgcn_rcpf(x);
}

// ---------- prep 1: Wx f32 -> f16 (GEMM B operand) ----------
__global__ void prep_wx(const float* __restrict__ Wx, ushort* __restrict__ Wxh) {
  int i = blockIdx.x * 256 + threadIdx.x;
  if (i < G3 * D_SZ) Wxh[i] = f2h(Wx[i]);
}

// ---------- prep 2: Wh -> per-thread packed f16-pair slots (r4 layout) ----------
//   tid<256 (i=tid):    s in [0,128): row=i      kp=s       (gate r, full row)
//                       s in [128,192): row=512+i kp=s-128  (gate n, k-lo half)
//   tid>=256 (i=tid-256): s in [0,128): row=256+i kp=s      (gate u, full row)
//                       s in [128,192): row=512+i kp=64+(s-128) (gate n, k-hi half)
// Storage (coalesced dwordx4): dword index = ((s>>2)*512 + tid)*4 + (s&3)
__global__ void prep_wq(const float* __restrict__ Wh, uint* __restrict__ Wq) {
  int idx = blockIdx.x * 256 + threadIdx.x; // 0 .. 192*512-1
  int s = idx >> 9;
  int tid = idx & 511;
  int row, kp;
  if (tid < 256) {
    if (s < 128) { row = tid;        kp = s; }
    else         { row = 512 + tid;  kp = s - 128; }
  } else {
    int i = tid - 256;
    if (s < 128) { row = 256 + i;    kp = s; }
    else         { row = 512 + i;    kp = 64 + (s - 128); }
  }
  float a = Wh[(size_t)row * D_SZ + 2 * kp];
  float b = Wh[(size_t)row * D_SZ + 2 * kp + 1];
  uint lo = (uint)f2h(a), hi = (uint)f2h(b);
  Wq[((size_t)(s >> 2) * 512 + tid) * 4 + (s & 3)] = lo | (hi << 16);
}

// ---------- GEMM: xs[m, g] = inputs[m, :] . Wx[g, :] + bx[g], stored f16 ----------
__global__ __launch_bounds__(256) void gemm_x(
    const float* __restrict__ A,   // [M_SZ, 256] f32
    const ushort* __restrict__ Bw, // Wx f16 [768, 256]
    const float* __restrict__ bx,  // [768] f32
    ushort* __restrict__ xs) {     // [M_SZ, 768] f16
  __shared__ _Float16 As[128][72];
  __shared__ _Float16 Bs[256][72];
  const int nt = blockIdx.x, mt = blockIdx.y;
  const int tid = threadIdx.x;
  const int lane = tid & 63, wv = tid >> 6;
  const int wr = (wv >> 1) * 64, wc = (wv & 1) * 128;
  const int l15 = lane & 15, l4 = lane >> 4;
  f32x4 acc[4][8] = {};
  for (int kt = 0; kt < 4; kt++) {
#pragma unroll
    for (int i = 0; i < 8; i++) {
      int f = tid + i * 256;
      int r = f >> 4, c4 = f & 15;
      float4 v = *(const float4*)(A + (size_t)(mt * 128 + r) * D_SZ + kt * 64 + c4 * 4);
      half4v h;
      h[0] = (_Float16)v.x; h[1] = (_Float16)v.y;
      h[2] = (_Float16)v.z; h[3] = (_Float16)v.w;
      *(half4v*)&As[r][c4 * 4] = h;
    }
#pragma unroll
    for (int i = 0; i < 8; i++) {
      int f = tid + i * 256;
      int r = f >> 3, c8 = f & 7;
      uint4 v = *(const uint4*)(Bw + (size_t)(nt * 256 + r) * D_SZ + kt * 64 + c8 * 8);
      *(uint4*)&Bs[r][c8 * 8] = v;
    }
    __syncthreads();
#pragma unroll
    for (int kk = 0; kk < 2; kk++) {
      half8v af[4], bf[8];
#pragma unroll
      for (int m = 0; m < 4; m++)
        af[m] = *(const half8v*)&As[wr + m * 16 + l15][kk * 32 + l4 * 8];
#pragma unroll
      for (int n = 0; n < 8; n++)
        bf[n] = *(const half8v*)&Bs[wc + n * 16 + l15][kk * 32 + l4 * 8];
#pragma unroll
      for (int m = 0; m < 4; m++) {
#pragma unroll
        for (int n = 0; n < 8; n++) {
          acc[m][n] = __builtin_amdgcn_mfma_f32_16x16x32_f16(af[m], bf[n], acc[m][n], 0, 0, 0);
        }
      }
    }
    __syncthreads();
  }
#pragma unroll
  for (int n = 0; n < 8; n++) {
    int col = nt * 256 + wc + n * 16 + l15;
    float bxv = bx[col];
#pragma unroll
    for (int m = 0; m < 4; m++) {
#pragma unroll
      for (int v4 = 0; v4 < 4; v4++) {
        int row = mt * 128 + wr + m * 16 + l4 * 4 + v4;
        xs[(size_t)row * G3 + col] = f2h(acc[m][n][v4] + bxv);
      }
    }
  }
}

// ---------- recurrence: 512 threads (8 waves, 2 waves/SIMD), VGPR pinned ------
// r4 structure verbatim (passed, 0 bank conflicts): tid<256 owns gate-r row i
// + n-row k-lo; tid>=256 owns gate-u row i + n-row k-hi. 192 weight dwords /
// thread. amdgpu_num_vgpr(240) pins the arch-VGPR allocation so the weight
// array lives in arch VGPRs (no AGPR split -> no v_accvgpr move tax, the 2x
// cost proven in r2-r11). h double-buffered in LDS (broadcast reads); 2 raw
// lgkm-only barriers/step; out-stores and x-loads stay in flight.
__global__ __launch_bounds__(512, 2) NUM_VGPR(240) NO_AGPR
void gru_rec(
    const ushort* __restrict__ xs, // [B, T, 768] f16
    const uint* __restrict__ Wq,   // packed per-thread weights
    const float* __restrict__ bh,  // [768]
    const float* __restrict__ hid, // [1, B, 256]
    float* __restrict__ out) {     // [B, T, 256] f32
  const int b = blockIdx.x;
  const int tid = threadIdx.x;
  const int i = tid & 255;
  const int nbase4 = (tid < 256) ? 0 : 16; // which h-quarter the n-half uses

  __shared__ alignas(16) ushort hbuf[2][H_SZ];
  __shared__ float us[H_SZ];
  __shared__ float nh[H_SZ];

  // 48 coalesced dwordx4 weight loads -> 192 registers
  uint w[192];
  {
    const uint4* wp = (const uint4*)Wq + tid;
#pragma unroll
    for (int s4 = 0; s4 < 48; s4++) {
      uint4 v = wp[(size_t)s4 * 512];
      w[4 * s4 + 0] = v.x; w[4 * s4 + 1] = v.y;
      w[4 * s4 + 2] = v.z; w[4 * s4 + 3] = v.w;
    }
  }
  const float bh_pre = bh[tid];           // r-bias (tid<256) or u-bias (tid>=256)
  const float bh_n = bh[512 + i];
  float hprev = 0.f;
  if (tid < 256) {
    hprev = hid[b * H_SZ + tid];
    hbuf[0][tid] = f2h(hprev);
  }
  __syncthreads();

  const ushort* xrow = xs + (size_t)b * T_SZ * G3;
  float* orow = out + (size_t)b * T_SZ * H_SZ + i;

  // x prefetch (1-step ahead): xa = own-gate pre-act, xb = x_n
  ushort xa_c = xrow[tid];
  ushort xb_c = xrow[512 + i];

#pragma unroll 1
  for (int t = 0; t < T_SZ; t++) {
    const ushort* xnxt = xrow + (t + 1 < T_SZ ? (size_t)(t + 1) * G3 : 0);
    ushort xa_n = xnxt[tid];
    ushort xb_n = xnxt[512 + i];

    // --- dots: 128 dot2 for the full gate row, 64 for the n-half ---
    float a0 = 0.f, a1 = 0.f, n0 = 0.f, n1 = 0.f;
    const uint4* hq = (const uint4*)hbuf[t & 1];
#pragma unroll
    for (int c = 0; c < 32; c++) {
      uint4 q = hq[c];
      a0 = fdot2f(w[4 * c + 0], q.x, a0);
      a1 = fdot2f(w[4 * c + 1], q.y, a1);
      a0 = fdot2f(w[4 * c + 2], q.z, a0);
      a1 = fdot2f(w[4 * c + 3], q.w, a1);
    }
#pragma unroll
    for (int c2 = 0; c2 < 16; c2++) {
      uint4 q = hq[nbase4 + c2];
      n0 = fdot2f(w[128 + 4 * c2 + 0], q.x, n0);
      n1 = fdot2f(w[128 + 4 * c2 + 1], q.y, n1);
      n0 = fdot2f(w[128 + 4 * c2 + 2], q.z, n0);
      n1 = fdot2f(w[128 + 4 * c2 + 3], q.w, n1);
    }
    float pre = a0 + a1 + bh_pre;
    float npart = n0 + n1;
    float sg = fast_rcp(1.f + __expf(-(h2f(xa_c) + pre))); // r (side0) / u (side1)

    if (tid >= 256) {
      us[i] = sg;
      nh[i] = npart;
    }
    asm volatile("s_waitcnt lgkmcnt(0)" ::: "memory");
    __builtin_amdgcn_s_barrier();

    if (tid < 256) {
      float u = us[i];
      float pre_n = npart + nh[i] + bh_n;
      float arg = h2f(xb_c) + sg * pre_n;
      float e = __expf(-2.f * fabsf(arg));
      float th = copysignf((1.f - e) * fast_rcp(1.f + e), arg);
      float hn = u * hprev + (1.f - u) * th;
      orow[(size_t)t * H_SZ] = hn;          // fire-and-forget
      hbuf[(t + 1) & 1][i] = f2h(hn);
      hprev = hn;
    }
    asm volatile("s_waitcnt lgkmcnt(0)" ::: "memory");
    __builtin_amdgcn_s_barrier();

    xa_c = xa_n;
    xb_c = xb_n;
  }
}

extern "C" void kernel_launch(void* const* d_in, const int* in_sizes, int n_in,
                              void* d_out, int out_size, void* d_ws, size_t ws_size,
                              hipStream_t stream) {
  const float* inp = (const float*)d_in[0]; // [B,T,D] f32
  const float* hid = (const float*)d_in[1]; // [1,B,H] f32
  const float* Wx  = (const float*)d_in[2]; // [768,256] f32
  const float* bx  = (const float*)d_in[3]; // [768] f32
  const float* Wh  = (const float*)d_in[4]; // [768,256] f32
  const float* bh  = (const float*)d_in[5]; // [768] f32
  float* out = (float*)d_out;

  // workspace: xs f16 [M_SZ,768] (192 MiB), Wxh f16 (384 KiB), Wq uint (384 KiB)
  char* ws = (char*)d_ws;
  ushort* xs = (ushort*)ws;
  size_t xs_bytes = (size_t)M_SZ * G3 * sizeof(ushort);
  ushort* Wxh = (ushort*)(ws + xs_bytes);
  uint* Wq = (uint*)(ws + xs_bytes + (size_t)G3 * D_SZ * sizeof(ushort));

  prep_wx<<<768, 256, 0, stream>>>(Wx, Wxh);
  prep_wq<<<384, 256, 0, stream>>>(Wh, Wq);
  gemm_x<<<dim3(3, 1024), 256, 0, stream>>>(inp, Wxh, bx, xs);
  gru_rec<<<B_SZ, 512, 0, stream>>>(xs, Wq, bh, hid, out);
}

// Round 14
// 2508.304 us; speedup vs baseline: 1.7560x; 1.1755x over previous
//
#include <hip/hip_runtime.h>
#include <hip/hip_fp16.h>

#define B_SZ 64
#define T_SZ 2048
#define D_SZ 256
#define H_SZ 256
#define G3   768
#define M_SZ (B_SZ * T_SZ) // 131072

typedef _Float16 half2v __attribute__((ext_vector_type(2)));
typedef _Float16 half4v __attribute__((ext_vector_type(4)));
typedef _Float16 half8v __attribute__((ext_vector_type(8)));
typedef float    f32x4  __attribute__((ext_vector_type(4)));

static __device__ __forceinline__ float fdot2f(uint a, uint b, float acc) {
#if __has_builtin(__builtin_amdgcn_fdot2)
  return __builtin_amdgcn_fdot2(__builtin_bit_cast(half2v, a),
                                __builtin_bit_cast(half2v, b), acc, false);
#else
  half2v av = __builtin_bit_cast(half2v, a), bv = __builtin_bit_cast(half2v, b);
  acc = fmaf((float)av[0], (float)bv[0], acc);
  acc = fmaf((float)av[1], (float)bv[1], acc);
  return acc;
#endif
}

static __device__ __forceinline__ float h2f(ushort u) {
  return (float)__builtin_bit_cast(_Float16, u);
}
static __device__ __forceinline__ ushort f2h(float x) {
  return __builtin_bit_cast(ushort, (_Float16)x);
}
static __device__ __forceinline__ float fast_rcp(float x) {
  return __builtin_amdgcn_rcpf(x);
}

// ---------- prep 1: Wx f32 -> f16 (GEMM B operand) ----------
__global__ void prep_wx(const float* __restrict__ Wx, ushort* __restrict__ Wxh) {
  int i = blockIdx.x * 256 + threadIdx.x;
  if (i < G3 * D_SZ) Wxh[i] = f2h(Wx[i]);
}

// ---------- prep 2: Wh -> packed f16-pair dwords, dwordx4-coalesced ----------
// gru_rec thread j (0..767) reads uint4 slot s4 (0..31) at (s4*768 + j).
// Slot s4's 4 dwords e=0..3 are h-pairs kp = 4*s4 + e of row j.
__global__ void prep_wq(const float* __restrict__ Wh, uint* __restrict__ Wq) {
  int f = blockIdx.x * 256 + threadIdx.x; // 0 .. 98303
  int e = f & 3;
  int t2 = f >> 2;
  int j = t2 % G3;
  int s4 = t2 / G3;     // 0..31
  int kp = 4 * s4 + e;  // 0..127
  float a = Wh[(size_t)j * D_SZ + 2 * kp];
  float b = Wh[(size_t)j * D_SZ + 2 * kp + 1];
  Wq[f] = (uint)f2h(a) | ((uint)f2h(b) << 16);
}

// ---------- GEMM: xs[m, g] = inputs[m, :] . Wx[g, :] + bx[g], stored f16 ----------
__global__ __launch_bounds__(256) void gemm_x(
    const float* __restrict__ A,   // [M_SZ, 256] f32
    const ushort* __restrict__ Bw, // Wx f16 [768, 256]
    const float* __restrict__ bx,  // [768] f32
    ushort* __restrict__ xs) {     // [M_SZ, 768] f16
  __shared__ _Float16 As[128][72];
  __shared__ _Float16 Bs[256][72];
  const int nt = blockIdx.x, mt = blockIdx.y;
  const int tid = threadIdx.x;
  const int lane = tid & 63, wv = tid >> 6;
  const int wr = (wv >> 1) * 64, wc = (wv & 1) * 128;
  const int l15 = lane & 15, l4 = lane >> 4;
  f32x4 acc[4][8] = {};
  for (int kt = 0; kt < 4; kt++) {
#pragma unroll
    for (int i = 0; i < 8; i++) {
      int f = tid + i * 256;
      int r = f >> 4, c4 = f & 15;
      float4 v = *(const float4*)(A + (size_t)(mt * 128 + r) * D_SZ + kt * 64 + c4 * 4);
      half4v h;
      h[0] = (_Float16)v.x; h[1] = (_Float16)v.y;
      h[2] = (_Float16)v.z; h[3] = (_Float16)v.w;
      *(half4v*)&As[r][c4 * 4] = h;
    }
#pragma unroll
    for (int i = 0; i < 8; i++) {
      int f = tid + i * 256;
      int r = f >> 3, c8 = f & 7;
      uint4 v = *(const uint4*)(Bw + (size_t)(nt * 256 + r) * D_SZ + kt * 64 + c8 * 8);
      *(uint4*)&Bs[r][c8 * 8] = v;
    }
    __syncthreads();
#pragma unroll
    for (int kk = 0; kk < 2; kk++) {
      half8v af[4], bf[8];
#pragma unroll
      for (int m = 0; m < 4; m++)
        af[m] = *(const half8v*)&As[wr + m * 16 + l15][kk * 32 + l4 * 8];
#pragma unroll
      for (int n = 0; n < 8; n++)
        bf[n] = *(const half8v*)&Bs[wc + n * 16 + l15][kk * 32 + l4 * 8];
#pragma unroll
      for (int m = 0; m < 4; m++) {
#pragma unroll
        for (int n = 0; n < 8; n++) {
          acc[m][n] = __builtin_amdgcn_mfma_f32_16x16x32_f16(af[m], bf[n], acc[m][n], 0, 0, 0);
        }
      }
    }
    __syncthreads();
  }
#pragma unroll
  for (int n = 0; n < 8; n++) {
    int col = nt * 256 + wc + n * 16 + l15;
    float bxv = bx[col];
#pragma unroll
    for (int m = 0; m < 4; m++) {
#pragma unroll
      for (int v4 = 0; v4 < 4; v4++) {
        int row = mt * 128 + wr + m * 16 + l4 * 4 + v4;
        xs[(size_t)row * G3 + col] = f2h(acc[m][n][v4] + bxv);
      }
    }
  }
}

// ---------- recurrence: 768 threads (12 waves, 3 waves/SIMD) ----------
// Best verified configuration (r6: 2382 us, 65% on-CU VALUBusy, 0 bank
// conflicts). Thread j owns pre-activation row j (w4[32] f16-pair dwords;
// ~half arch-VGPR-resident, half AGPR with compiler moves — proven
// unavoidable in r7-r13). h broadcast from LDS (uniform addresses ->
// conflict-free, ~free BW). 2 raw lgkm-only barriers/step; out-stores and
// x-loads stay in flight across barriers.
__global__ __launch_bounds__(768, 3) void gru_rec(
    const ushort* __restrict__ xs, // [B, T, 768] f16
    const uint* __restrict__ Wq,   // packed per-thread weights
    const float* __restrict__ bh,  // [768]
    const float* __restrict__ hid, // [1, B, 256]
    float* __restrict__ out) {     // [B, T, 256] f32
  const int b = blockIdx.x;
  const int j = threadIdx.x;
  __shared__ alignas(16) ushort h16[H_SZ];
  __shared__ float rs[H_SZ];
  __shared__ float us[H_SZ];

  // 32 coalesced dwordx4 weight loads -> 128 registers
  uint4 w4[32];
  {
    const uint4* wp = (const uint4*)Wq;
#pragma unroll
    for (int s4 = 0; s4 < 32; s4++) w4[s4] = wp[(size_t)s4 * G3 + j];
  }
  const float bhj = bh[j];
  if (j < H_SZ) h16[j] = f2h(hid[b * H_SZ + j]);
  __syncthreads();

  const ushort* xrow = xs + (size_t)b * T_SZ * G3 + j;
  float* orow = out + (size_t)b * T_SZ * H_SZ;
  ushort xu = xrow[0];

#pragma unroll 1
  for (int t = 0; t < T_SZ; t++) {
    // prefetch next step's x (latency hides under the dot chain)
    ushort xnext = (t + 1 < T_SZ) ? xrow[(size_t)(t + 1) * G3] : (ushort)0;
    float x = h2f(xu);

    // dot: Wh[j,:] . h  (128 dot2, 4 chains, h broadcast from LDS)
    float d0 = 0.f, d1 = 0.f, d2 = 0.f, d3 = 0.f;
    const uint4* hq = (const uint4*)h16;
#pragma unroll
    for (int c = 0; c < 32; c++) {
      uint4 q = hq[c];
      uint4 wv = w4[c];
      d0 = fdot2f(wv.x, q.x, d0);
      d1 = fdot2f(wv.y, q.y, d1);
      d2 = fdot2f(wv.z, q.z, d2);
      d3 = fdot2f(wv.w, q.w, d3);
    }
    float pre = ((d0 + d1) + (d2 + d3)) + bhj;

    if (j < 512) {
      float a = pre + x;                  // x_r + h_r  |  x_u + h_u
      float s = fast_rcp(1.f + __expf(-a));
      if (j < H_SZ) rs[j] = s;
      else          us[j - H_SZ] = s;
    }
    asm volatile("s_waitcnt lgkmcnt(0)" ::: "memory");
    __builtin_amdgcn_s_barrier();

    if (j >= 512) {                       // gate-n threads do the combine
      int i = j - 512;
      float r = rs[i], u = us[i];
      float hold = h2f(h16[i]);
      float arg = x + r * pre;            // x_n + reset*h_n
      float e = __expf(-2.f * fabsf(arg));
      float th = copysignf((1.f - e) * fast_rcp(1.f + e), arg);
      float hn = u * hold + (1.f - u) * th;
      orow[(size_t)t * H_SZ + i] = hn;    // fire-and-forget
      h16[i] = f2h(hn);
    }
    asm volatile("s_waitcnt lgkmcnt(0)" ::: "memory");
    __builtin_amdgcn_s_barrier();
    xu = xnext;
  }
}

extern "C" void kernel_launch(void* const* d_in, const int* in_sizes, int n_in,
                              void* d_out, int out_size, void* d_ws, size_t ws_size,
                              hipStream_t stream) {
  const float* inp = (const float*)d_in[0]; // [B,T,D] f32
  const float* hid = (const float*)d_in[1]; // [1,B,H] f32
  const float* Wx  = (const float*)d_in[2]; // [768,256] f32
  const float* bx  = (const float*)d_in[3]; // [768] f32
  const float* Wh  = (const float*)d_in[4]; // [768,256] f32
  const float* bh  = (const float*)d_in[5]; // [768] f32
  float* out = (float*)d_out;

  // workspace: xs f16 [M_SZ,768] (192 MiB), Wxh f16 (384 KiB), Wq uint (384 KiB)
  char* ws = (char*)d_ws;
  ushort* xs = (ushort*)ws;
  size_t xs_bytes = (size_t)M_SZ * G3 * sizeof(ushort);
  ushort* Wxh = (ushort*)(ws + xs_bytes);
  uint* Wq = (uint*)(ws + xs_bytes + (size_t)G3 * D_SZ * sizeof(ushort));

  prep_wx<<<768, 256, 0, stream>>>(Wx, Wxh);
  prep_wq<<<384, 256, 0, stream>>>(Wh, Wq);
  gemm_x<<<dim3(3, 1024), 256, 0, stream>>>(inp, Wxh, bx, xs);
  gru_rec<<<B_SZ, G3, 0, stream>>>(xs, Wq, bh, hid, out);
}